// Round 14
// baseline (42.444 us; speedup 1.0000x reference)
//
#include <hip/hip_runtime.h>

// CRF NLL v12 = v9 verified math, SINGLE kernel:
//   per-block partial -> device-scope atomicExch(part[bid]) (memory-side, no L2 aliasing)
//   -> __threadfence -> atomicAdd(counter); last block acquires + reduces 512 partials
//   -> plain store out[0].  No second kernel, no same-address float atomics.
// Counter zeroed per launch via 4-byte hipMemsetAsync (graph-safe).

typedef float f32x4 __attribute__((ext_vector_type(4)));
typedef __bf16 bf16x8 __attribute__((ext_vector_type(8)));
typedef unsigned int u32x4 __attribute__((ext_vector_type(4)));
typedef unsigned int u32x2 __attribute__((ext_vector_type(2)));

#define C_SCALE 1.4426950408889634f  // 1/ln2
#define LN2 0.6931471805599453f
#define NEGF (-3.0e38f)

__device__ __forceinline__ unsigned short f2bf(float f) {
    unsigned u = __float_as_uint(f);
    u += 0x7fffu + ((u >> 16) & 1u);   // RNE
    return (unsigned short)(u >> 16);
}

__device__ __forceinline__ float lo16f(unsigned u) { return __uint_as_float(u << 16); }
__device__ __forceinline__ float hi16f(unsigned u) { return __uint_as_float(u & 0xFFFF0000u); }

__device__ __forceinline__ float qmax(float x) {
    float y = fmaxf(x, __shfl_xor(x, 16, 64));
    u32x2 r = __builtin_amdgcn_permlane32_swap(__float_as_uint(y), __float_as_uint(y), false, false);
    return fmaxf(__uint_as_float(r[0]), __uint_as_float(r[1]));
}
__device__ __forceinline__ float qsum(float x) {
    float y = x + __shfl_xor(x, 16, 64);
    u32x2 r = __builtin_amdgcn_permlane32_swap(__float_as_uint(y), __float_as_uint(y), false, false);
    return __uint_as_float(r[0]) + __uint_as_float(r[1]);
}

union ABu { unsigned int w[4]; bf16x8 b; unsigned short u[8]; };

__device__ __forceinline__ bf16x8 pack_bf8(f32x4 a, f32x4 b) {
    ABu r;
    r.u[0] = f2bf(a[0]); r.u[1] = f2bf(a[1]); r.u[2] = f2bf(a[2]); r.u[3] = f2bf(a[3]);
    r.u[4] = f2bf(b[0]); r.u[5] = f2bf(b[1]); r.u[6] = f2bf(b[2]); r.u[7] = f2bf(b[3]);
    return r.b;
}

__global__ __launch_bounds__(256, 2) void crf_kernel(
    const float* __restrict__ X, const int* __restrict__ Y,
    const float* __restrict__ W, const float* __restrict__ T,
    float* __restrict__ part, unsigned* __restrict__ cnt,
    float* __restrict__ out, int nblocks)
{
    __shared__ unsigned e_lds[320 * 20];  // packed bf16 pairs, row stride 20 words (80B)
    __shared__ float t_lds[26 * 26];      // T natural domain
    __shared__ float red1;                // wave-1 partial

    const int tid = threadIdx.x;
    const int w   = tid >> 6;
    const int l   = tid & 63;
    const int c0  = l & 15, kg = l >> 4;

    for (int i = tid; i < 676; i += 256) t_lds[i] = T[i];

    // ---- Phase A (verified) ----
    {
        ABu bfrag[4][2];
        const int koff = kg * 8;
        #pragma unroll
        for (int kk = 0; kk < 4; ++kk) {
            #pragma unroll
            for (int nt = 0; nt < 2; ++nt) {
                const int col = nt * 16 + c0;
                ABu f;
                if (col < 26) {
                    const float* wp = W + col * 128 + kk * 32 + koff;
                    f32x4 w0 = *(const f32x4*)wp;
                    f32x4 w1 = *(const f32x4*)(wp + 4);
                    f.b = pack_bf8(w0, w1);
                } else {
                    f.w[0] = f.w[1] = f.w[2] = f.w[3] = 0u;
                }
                bfrag[kk][nt] = f;
            }
        }
        const int rbase = w * 80;
        for (int t = 0; t < 5; ++t) {
            const float* xp = X + ((long)blockIdx.x * 320 + rbase + t * 16 + c0) * 128 + kg * 8;
            f32x4 acc0 = {0.f,0.f,0.f,0.f}, acc1 = {0.f,0.f,0.f,0.f};
            #pragma unroll
            for (int kk = 0; kk < 4; ++kk) {
                f32x4 x0 = *(const f32x4*)(xp + kk * 32);
                f32x4 x1 = *(const f32x4*)(xp + kk * 32 + 4);
                bf16x8 a = pack_bf8(x0, x1);
                acc0 = __builtin_amdgcn_mfma_f32_16x16x32_bf16(a, bfrag[kk][0].b, acc0, 0, 0, 0);
                acc1 = __builtin_amdgcn_mfma_f32_16x16x32_bf16(a, bfrag[kk][1].b, acc1, 0, 0, 0);
            }
            #pragma unroll
            for (int i = 0; i < 4; ++i) {
                const int rr = rbase + t * 16 + kg * 4 + i;
                const unsigned wlo = f2bf(acc0[i] * C_SCALE);
                const unsigned whi = f2bf(acc1[i] * C_SCALE);
                e_lds[rr * 20 + c0] = (whi << 16) | wlo;
            }
        }
    }
    __syncthreads();

    const int g = l >> 4, c = l & 15;
    const int elem = blockIdx.x * 16 + c;

    float myv = 0.f;

    // ---- Wave 1: node + edge potentials ----
    if (w == 1) {
        const int ebase = elem * 20;
        float nd2 = 0.f, edn = 0.f;
        int y[6];
        #pragma unroll
        for (int t = 0; t < 5; ++t) y[t] = Y[ebase + 5 * g + t];
        y[5] = (g < 3) ? Y[ebase + 5 * g + 5] : 0;
        #pragma unroll
        for (int t = 0; t < 5; ++t) {
            const int m = 5 * g + t;
            const unsigned wv = e_lds[(c * 20 + m) * 20 + (y[t] & 15)];
            nd2 += (y[t] < 16) ? lo16f(wv) : hi16f(wv);
            if (m < 19) edn += t_lds[y[t] * 26 + y[t + 1]];
        }
        float v = -LN2 * nd2 - edn;
        #pragma unroll
        for (int d = 1; d <= 32; d <<= 1) v += __shfl_xor(v, d, 64);
        if (l == 0) red1 = v;
    }

    // ---- Wave 0: MFMA-matvec recursion (verified) ----
    if (w == 0) {
        ABu A0, A1;
        #pragma unroll
        for (int jj = 0; jj < 8; ++jj) {
            const int kp = 4 * g + (jj & 3) + ((jj >> 2) << 4);
            float v0 = 0.f, v1 = 0.f;
            if (kp < 26) {
                v0 = __builtin_amdgcn_exp2f(t_lds[kp * 26 + c] * C_SCALE);
                if (16 + c < 26) v1 = __builtin_amdgcn_exp2f(t_lds[kp * 26 + 16 + c] * C_SCALE);
            }
            A0.u[jj] = f2bf(v0);
            A1.u[jj] = f2bf(v1);
        }

        u32x4 ev[20];
        #pragma unroll
        for (int m = 0; m < 20; ++m)
            ev[m] = *(const u32x4*)&e_lds[c * 400 + m * 20 + 4 * g];

        f32x4 s0, s1;
        #pragma unroll
        for (int i = 0; i < 4; ++i) { s0[i] = lo16f(ev[0][i]); s1[i] = hi16f(ev[0][i]); }
        if (16 + 4 * g + 0 >= 26) s1[0] = NEGF;
        if (16 + 4 * g + 1 >= 26) s1[1] = NEGF;
        if (16 + 4 * g + 2 >= 26) s1[2] = NEGF;
        if (16 + 4 * g + 3 >= 26) s1[3] = NEGF;

        const f32x4 z = {0.f, 0.f, 0.f, 0.f};
        #pragma unroll
        for (int m = 0; m < 19; ++m) {
            const float mx8 = fmaxf(fmaxf(fmaxf(s0[0], s0[1]), fmaxf(s0[2], s0[3])),
                                    fmaxf(fmaxf(s1[0], s1[1]), fmaxf(s1[2], s1[3])));
            const float mx = qmax(mx8);
            ABu B;
            B.u[0] = f2bf(__builtin_amdgcn_exp2f(s0[0] - mx));
            B.u[1] = f2bf(__builtin_amdgcn_exp2f(s0[1] - mx));
            B.u[2] = f2bf(__builtin_amdgcn_exp2f(s0[2] - mx));
            B.u[3] = f2bf(__builtin_amdgcn_exp2f(s0[3] - mx));
            B.u[4] = f2bf(__builtin_amdgcn_exp2f(s1[0] - mx));
            B.u[5] = f2bf(__builtin_amdgcn_exp2f(s1[1] - mx));
            B.u[6] = f2bf(__builtin_amdgcn_exp2f(s1[2] - mx));
            B.u[7] = f2bf(__builtin_amdgcn_exp2f(s1[3] - mx));
            f32x4 D0 = __builtin_amdgcn_mfma_f32_16x16x32_bf16(A0.b, B.b, z, 0, 0, 0);
            f32x4 D1 = __builtin_amdgcn_mfma_f32_16x16x32_bf16(A1.b, B.b, z, 0, 0, 0);
            #pragma unroll
            for (int i = 0; i < 4; ++i) {
                s0[i] = mx + __builtin_amdgcn_logf(D0[i]) + lo16f(ev[m + 1][i]);
                s1[i] = mx + __builtin_amdgcn_logf(D1[i]) + hi16f(ev[m + 1][i]);
            }
        }

        const float mxl = fmaxf(fmaxf(fmaxf(s0[0], s0[1]), fmaxf(s0[2], s0[3])),
                                fmaxf(fmaxf(s1[0], s1[1]), fmaxf(s1[2], s1[3])));
        const float mx2 = qmax(mxl);
        float sm = __builtin_amdgcn_exp2f(s0[0] - mx2) + __builtin_amdgcn_exp2f(s0[1] - mx2)
                 + __builtin_amdgcn_exp2f(s0[2] - mx2) + __builtin_amdgcn_exp2f(s0[3] - mx2)
                 + __builtin_amdgcn_exp2f(s1[0] - mx2) + __builtin_amdgcn_exp2f(s1[1] - mx2)
                 + __builtin_amdgcn_exp2f(s1[2] - mx2) + __builtin_amdgcn_exp2f(s1[3] - mx2);
        sm = qsum(sm);
        const float logZ2 = mx2 + __builtin_amdgcn_logf(sm);

        float v = (g == 0) ? LN2 * logZ2 : 0.f;
        #pragma unroll
        for (int d = 1; d <= 32; d <<= 1) v += __shfl_xor(v, d, 64);
        myv = v;
    }

    __syncthreads();   // red1 visible to wave 0

    // ---- Last-block reduction (wave 0 only; no second kernel) ----
    if (w == 0) {
        int isLast = 0;
        if (l == 0) {
            atomicExch(&part[blockIdx.x], myv + red1);  // device-scope, memory-side
            __threadfence();                             // release
            isLast = (atomicAdd(cnt, 1u) == (unsigned)(nblocks - 1));
        }
        isLast = __shfl(isLast, 0, 64);
        if (isLast) {
            __threadfence();                             // acquire
            float v = 0.f;
            for (int i = l; i < nblocks; i += 64) v += part[i];
            #pragma unroll
            for (int d = 1; d <= 32; d <<= 1) v += __shfl_xor(v, d, 64);
            if (l == 0) out[0] = v;
        }
    }
}

extern "C" void kernel_launch(void* const* d_in, const int* in_sizes, int n_in,
                              void* d_out, int out_size, void* d_ws, size_t ws_size,
                              hipStream_t stream) {
    const float* X = (const float*)d_in[0];
    const int*   Y = (const int*)d_in[1];
    const float* W = (const float*)d_in[2];
    const float* T = (const float*)d_in[3];
    float* out = (float*)d_out;
    float* part = (float*)d_ws;                              // 512 floats
    unsigned* cnt = (unsigned*)((char*)d_ws + 4096);         // separate line

    const int B = in_sizes[1] / 20;        // 8192
    const int nblocks = B / 16;            // 512

    hipMemsetAsync(cnt, 0, 4, stream);
    crf_kernel<<<nblocks, 256, 0, stream>>>(X, Y, W, T, part, cnt, out, nblocks);
}

// Round 15
// 35.685 us; speedup vs baseline: 1.1894x; 1.1894x over previous
//
#include <hip/hip_runtime.h>

// CRF NLL v14: wave-decoupled fused kernel + tiny reduce kernel.
// Each of the 4 waves per block independently: 5-tile emission MFMA (own 4 elems,
// verified math) -> bf16-packed LDS -> own 4-elem MFMA-matvec chain (verified math,
// cols 0-3 real, c&3 duplicates) -> own node/edge -> partial store part[4*bid+w].
// NO __syncthreads, no t_lds, no atomics. reduce_kernel sums 2048 partials -> out.

typedef float f32x4 __attribute__((ext_vector_type(4)));
typedef __bf16 bf16x8 __attribute__((ext_vector_type(8)));
typedef unsigned int u32x4 __attribute__((ext_vector_type(4)));
typedef unsigned int u32x2 __attribute__((ext_vector_type(2)));

#define C_SCALE 1.4426950408889634f  // 1/ln2
#define LN2 0.6931471805599453f
#define NEGF (-3.0e38f)

__device__ __forceinline__ unsigned short f2bf(float f) {
    unsigned u = __float_as_uint(f);
    u += 0x7fffu + ((u >> 16) & 1u);   // RNE
    return (unsigned short)(u >> 16);
}

__device__ __forceinline__ float lo16f(unsigned u) { return __uint_as_float(u << 16); }
__device__ __forceinline__ float hi16f(unsigned u) { return __uint_as_float(u & 0xFFFF0000u); }

__device__ __forceinline__ float qmax(float x) {
    float y = fmaxf(x, __shfl_xor(x, 16, 64));
    u32x2 r = __builtin_amdgcn_permlane32_swap(__float_as_uint(y), __float_as_uint(y), false, false);
    return fmaxf(__uint_as_float(r[0]), __uint_as_float(r[1]));
}
__device__ __forceinline__ float qsum(float x) {
    float y = x + __shfl_xor(x, 16, 64);
    u32x2 r = __builtin_amdgcn_permlane32_swap(__float_as_uint(y), __float_as_uint(y), false, false);
    return __uint_as_float(r[0]) + __uint_as_float(r[1]);
}

union ABu { unsigned int w[4]; bf16x8 b; unsigned short u[8]; };

__device__ __forceinline__ bf16x8 pack_bf8(f32x4 a, f32x4 b) {
    ABu r;
    r.u[0] = f2bf(a[0]); r.u[1] = f2bf(a[1]); r.u[2] = f2bf(a[2]); r.u[3] = f2bf(a[3]);
    r.u[4] = f2bf(b[0]); r.u[5] = f2bf(b[1]); r.u[6] = f2bf(b[2]); r.u[7] = f2bf(b[3]);
    return r.b;
}

__global__ __launch_bounds__(256, 2) void crf_kernel(
    const float* __restrict__ X, const int* __restrict__ Y,
    const float* __restrict__ W, const float* __restrict__ T,
    float* __restrict__ part)
{
    __shared__ unsigned e_lds[320 * 20];  // packed bf16 pairs, row stride 20 words

    const int tid = threadIdx.x;
    const int w   = tid >> 6;
    const int l   = tid & 63;
    const int c0  = l & 15, kg = l >> 4;

    // ---- Phase A (verified): W B-frags, wave's own 5 tiles (rows w*80..w*80+79) ----
    {
        ABu bfrag[4][2];
        const int koff = kg * 8;
        #pragma unroll
        for (int kk = 0; kk < 4; ++kk) {
            #pragma unroll
            for (int nt = 0; nt < 2; ++nt) {
                const int col = nt * 16 + c0;
                ABu f;
                if (col < 26) {
                    const float* wp = W + col * 128 + kk * 32 + koff;
                    f32x4 w0 = *(const f32x4*)wp;
                    f32x4 w1 = *(const f32x4*)(wp + 4);
                    f.b = pack_bf8(w0, w1);
                } else {
                    f.w[0] = f.w[1] = f.w[2] = f.w[3] = 0u;
                }
                bfrag[kk][nt] = f;
            }
        }
        const int rbase = w * 80;
        for (int t = 0; t < 5; ++t) {
            const float* xp = X + ((long)blockIdx.x * 320 + rbase + t * 16 + c0) * 128 + kg * 8;
            f32x4 acc0 = {0.f,0.f,0.f,0.f}, acc1 = {0.f,0.f,0.f,0.f};
            #pragma unroll
            for (int kk = 0; kk < 4; ++kk) {
                f32x4 x0 = *(const f32x4*)(xp + kk * 32);
                f32x4 x1 = *(const f32x4*)(xp + kk * 32 + 4);
                bf16x8 a = pack_bf8(x0, x1);
                acc0 = __builtin_amdgcn_mfma_f32_16x16x32_bf16(a, bfrag[kk][0].b, acc0, 0, 0, 0);
                acc1 = __builtin_amdgcn_mfma_f32_16x16x32_bf16(a, bfrag[kk][1].b, acc1, 0, 0, 0);
            }
            // C/D: col=lane&15, row=kg*4+i [verified]
            #pragma unroll
            for (int i = 0; i < 4; ++i) {
                const int rr = rbase + t * 16 + kg * 4 + i;
                const unsigned wlo = f2bf(acc0[i] * C_SCALE);
                const unsigned whi = f2bf(acc1[i] * C_SCALE);
                e_lds[rr * 20 + c0] = (whi << 16) | wlo;
            }
        }
    }
    // NO barrier: this wave only reads rows it wrote (same-wave LDS RAW via lgkmcnt)

    const int g = l >> 4, c = l & 15;
    const int ce = c & 3;                 // real elem for cols 0-3; 4-15 duplicate

    // ---- A-fragments from global T (L2-resident): A[m][k'] = E[pi(k')][m] [verified] ----
    ABu A0, A1;
    #pragma unroll
    for (int jj = 0; jj < 8; ++jj) {
        const int kp = 4 * g + (jj & 3) + ((jj >> 2) << 4);
        float v0 = 0.f, v1 = 0.f;
        if (kp < 26) {
            v0 = __builtin_amdgcn_exp2f(T[kp * 26 + c] * C_SCALE);
            if (16 + c < 26) v1 = __builtin_amdgcn_exp2f(T[kp * 26 + 16 + c] * C_SCALE);
        }
        A0.u[jj] = f2bf(v0);
        A1.u[jj] = f2bf(v1);
    }

    // ---- prefetch own-elem emissions: row = w*80 + ce*20 + m ----
    u32x4 ev[20];
    #pragma unroll
    for (int m = 0; m < 20; ++m)
        ev[m] = *(const u32x4*)&e_lds[(w * 80 + ce * 20 + m) * 20 + 4 * g];

    f32x4 s0, s1;
    #pragma unroll
    for (int i = 0; i < 4; ++i) { s0[i] = lo16f(ev[0][i]); s1[i] = hi16f(ev[0][i]); }
    if (16 + 4 * g + 0 >= 26) s1[0] = NEGF;
    if (16 + 4 * g + 1 >= 26) s1[1] = NEGF;
    if (16 + 4 * g + 2 >= 26) s1[2] = NEGF;
    if (16 + 4 * g + 3 >= 26) s1[3] = NEGF;

    const f32x4 z = {0.f, 0.f, 0.f, 0.f};
    #pragma unroll
    for (int m = 0; m < 19; ++m) {
        const float mx8 = fmaxf(fmaxf(fmaxf(s0[0], s0[1]), fmaxf(s0[2], s0[3])),
                                fmaxf(fmaxf(s1[0], s1[1]), fmaxf(s1[2], s1[3])));
        const float mx = qmax(mx8);
        ABu B;
        B.u[0] = f2bf(__builtin_amdgcn_exp2f(s0[0] - mx));
        B.u[1] = f2bf(__builtin_amdgcn_exp2f(s0[1] - mx));
        B.u[2] = f2bf(__builtin_amdgcn_exp2f(s0[2] - mx));
        B.u[3] = f2bf(__builtin_amdgcn_exp2f(s0[3] - mx));
        B.u[4] = f2bf(__builtin_amdgcn_exp2f(s1[0] - mx));
        B.u[5] = f2bf(__builtin_amdgcn_exp2f(s1[1] - mx));
        B.u[6] = f2bf(__builtin_amdgcn_exp2f(s1[2] - mx));
        B.u[7] = f2bf(__builtin_amdgcn_exp2f(s1[3] - mx));
        f32x4 D0 = __builtin_amdgcn_mfma_f32_16x16x32_bf16(A0.b, B.b, z, 0, 0, 0);
        f32x4 D1 = __builtin_amdgcn_mfma_f32_16x16x32_bf16(A1.b, B.b, z, 0, 0, 0);
        #pragma unroll
        for (int i = 0; i < 4; ++i) {
            s0[i] = mx + __builtin_amdgcn_logf(D0[i]) + lo16f(ev[m + 1][i]);
            s1[i] = mx + __builtin_amdgcn_logf(D1[i]) + hi16f(ev[m + 1][i]);
        }
    }

    // logZ per column (replicated across the 4-lane quad)
    const float mxl = fmaxf(fmaxf(fmaxf(s0[0], s0[1]), fmaxf(s0[2], s0[3])),
                            fmaxf(fmaxf(s1[0], s1[1]), fmaxf(s1[2], s1[3])));
    const float mx2 = qmax(mxl);
    float sm = __builtin_amdgcn_exp2f(s0[0] - mx2) + __builtin_amdgcn_exp2f(s0[1] - mx2)
             + __builtin_amdgcn_exp2f(s0[2] - mx2) + __builtin_amdgcn_exp2f(s0[3] - mx2)
             + __builtin_amdgcn_exp2f(s1[0] - mx2) + __builtin_amdgcn_exp2f(s1[1] - mx2)
             + __builtin_amdgcn_exp2f(s1[2] - mx2) + __builtin_amdgcn_exp2f(s1[3] - mx2);
    sm = qsum(sm);
    const float logZ2 = mx2 + __builtin_amdgcn_logf(sm);

    // ---- node + edge for this wave's 4 elems: lanes (g, c<4), timesteps 5g..5g+4 ----
    float v = 0.f;
    if (c < 4) {
        const int eglob = blockIdx.x * 16 + 4 * w + c;
        float nd2 = 0.f, edn = 0.f;
        int y[6];
        #pragma unroll
        for (int t = 0; t < 5; ++t) y[t] = Y[eglob * 20 + 5 * g + t];
        y[5] = (g < 3) ? Y[eglob * 20 + 5 * g + 5] : 0;
        #pragma unroll
        for (int t = 0; t < 5; ++t) {
            const int m = 5 * g + t;
            const unsigned wv = e_lds[(w * 80 + c * 20 + m) * 20 + (y[t] & 15)];
            nd2 += (y[t] < 16) ? lo16f(wv) : hi16f(wv);
            if (m < 19) edn += T[y[t] * 26 + y[t + 1]];
        }
        v = -LN2 * nd2 - edn;
        if (g == 0) v += LN2 * logZ2;   // one logZ per real elem
    }
    #pragma unroll
    for (int d = 1; d <= 32; d <<= 1) v += __shfl_xor(v, d, 64);
    if (l == 0) part[blockIdx.x * 4 + w] = v;   // plain store, per wave
}

__global__ __launch_bounds__(256) void reduce_kernel(
    const float* __restrict__ part, float* __restrict__ out, int n)
{
    __shared__ float s[4];
    const int tid = threadIdx.x;
    float v = 0.f;
    for (int i = tid; i < n; i += 256) v += part[i];
    #pragma unroll
    for (int d = 1; d <= 32; d <<= 1) v += __shfl_xor(v, d, 64);
    if ((tid & 63) == 0) s[tid >> 6] = v;
    __syncthreads();
    if (tid == 0) out[0] = s[0] + s[1] + s[2] + s[3];
}

extern "C" void kernel_launch(void* const* d_in, const int* in_sizes, int n_in,
                              void* d_out, int out_size, void* d_ws, size_t ws_size,
                              hipStream_t stream) {
    const float* X = (const float*)d_in[0];
    const int*   Y = (const int*)d_in[1];
    const float* W = (const float*)d_in[2];
    const float* T = (const float*)d_in[3];
    float* out = (float*)d_out;
    float* part = (float*)d_ws;            // 2048 floats

    const int B = in_sizes[1] / 20;        // 8192
    const int nblocks = B / 16;            // 512

    crf_kernel<<<nblocks, 256, 0, stream>>>(X, Y, W, T, part);
    reduce_kernel<<<1, 256, 0, stream>>>(part, out, nblocks * 4);
}

// Round 16
// 32.887 us; speedup vs baseline: 1.2906x; 1.0851x over previous
//
#include <hip/hip_runtime.h>

// CRF NLL v15 = v9 verified math at half block-granularity for 2x memory-level parallelism:
// 1024 blocks x 256 threads, 8 elems/block. Phase A: 10 tiles round-robin over 4 waves
// (verified tile math), bf16-packed e in LDS. Phase B: wave 0 = verified MFMA-matvec chain
// (cols 0-7 real, c&7 duplicates), wave 1 = node/edge. Two partials/block -> reduce kernel.
// No atomics, no t_lds (T reads from global, L2-resident; verified round 15).

typedef float f32x4 __attribute__((ext_vector_type(4)));
typedef __bf16 bf16x8 __attribute__((ext_vector_type(8)));
typedef unsigned int u32x4 __attribute__((ext_vector_type(4)));
typedef unsigned int u32x2 __attribute__((ext_vector_type(2)));

#define C_SCALE 1.4426950408889634f  // 1/ln2
#define LN2 0.6931471805599453f
#define NEGF (-3.0e38f)

__device__ __forceinline__ unsigned short f2bf(float f) {
    unsigned u = __float_as_uint(f);
    u += 0x7fffu + ((u >> 16) & 1u);   // RNE
    return (unsigned short)(u >> 16);
}

__device__ __forceinline__ float lo16f(unsigned u) { return __uint_as_float(u << 16); }
__device__ __forceinline__ float hi16f(unsigned u) { return __uint_as_float(u & 0xFFFF0000u); }

__device__ __forceinline__ float qmax(float x) {
    float y = fmaxf(x, __shfl_xor(x, 16, 64));
    u32x2 r = __builtin_amdgcn_permlane32_swap(__float_as_uint(y), __float_as_uint(y), false, false);
    return fmaxf(__uint_as_float(r[0]), __uint_as_float(r[1]));
}
__device__ __forceinline__ float qsum(float x) {
    float y = x + __shfl_xor(x, 16, 64);
    u32x2 r = __builtin_amdgcn_permlane32_swap(__float_as_uint(y), __float_as_uint(y), false, false);
    return __uint_as_float(r[0]) + __uint_as_float(r[1]);
}

union ABu { unsigned int w[4]; bf16x8 b; unsigned short u[8]; };

__device__ __forceinline__ bf16x8 pack_bf8(f32x4 a, f32x4 b) {
    ABu r;
    r.u[0] = f2bf(a[0]); r.u[1] = f2bf(a[1]); r.u[2] = f2bf(a[2]); r.u[3] = f2bf(a[3]);
    r.u[4] = f2bf(b[0]); r.u[5] = f2bf(b[1]); r.u[6] = f2bf(b[2]); r.u[7] = f2bf(b[3]);
    return r.b;
}

__global__ __launch_bounds__(256, 2) void crf_kernel(
    const float* __restrict__ X, const int* __restrict__ Y,
    const float* __restrict__ W, const float* __restrict__ T,
    float* __restrict__ part)
{
    __shared__ unsigned e_lds[160 * 20];  // 8 elems x 20 steps, packed bf16 pairs
    __shared__ float red1;                // unused placeholder removed; keep layout simple

    const int tid = threadIdx.x;
    const int w   = tid >> 6;
    const int l   = tid & 63;
    const int c0  = l & 15, kg = l >> 4;

    // ---- Phase A (verified tile math): 10 tiles round-robin over 4 waves ----
    {
        ABu bfrag[4][2];
        const int koff = kg * 8;
        #pragma unroll
        for (int kk = 0; kk < 4; ++kk) {
            #pragma unroll
            for (int nt = 0; nt < 2; ++nt) {
                const int col = nt * 16 + c0;
                ABu f;
                if (col < 26) {
                    const float* wp = W + col * 128 + kk * 32 + koff;
                    f32x4 w0 = *(const f32x4*)wp;
                    f32x4 w1 = *(const f32x4*)(wp + 4);
                    f.b = pack_bf8(w0, w1);
                } else {
                    f.w[0] = f.w[1] = f.w[2] = f.w[3] = 0u;
                }
                bfrag[kk][nt] = f;
            }
        }
        for (int t = w; t < 10; t += 4) {
            const float* xp = X + ((long)blockIdx.x * 160 + t * 16 + c0) * 128 + kg * 8;
            f32x4 acc0 = {0.f,0.f,0.f,0.f}, acc1 = {0.f,0.f,0.f,0.f};
            #pragma unroll
            for (int kk = 0; kk < 4; ++kk) {
                f32x4 x0 = *(const f32x4*)(xp + kk * 32);
                f32x4 x1 = *(const f32x4*)(xp + kk * 32 + 4);
                bf16x8 a = pack_bf8(x0, x1);
                acc0 = __builtin_amdgcn_mfma_f32_16x16x32_bf16(a, bfrag[kk][0].b, acc0, 0, 0, 0);
                acc1 = __builtin_amdgcn_mfma_f32_16x16x32_bf16(a, bfrag[kk][1].b, acc1, 0, 0, 0);
            }
            // C/D: col=lane&15, row=kg*4+i [verified]
            #pragma unroll
            for (int i = 0; i < 4; ++i) {
                const int rr = t * 16 + kg * 4 + i;
                const unsigned wlo = f2bf(acc0[i] * C_SCALE);
                const unsigned whi = f2bf(acc1[i] * C_SCALE);
                e_lds[rr * 20 + c0] = (whi << 16) | wlo;
            }
        }
    }
    __syncthreads();

    const int g = l >> 4, c = l & 15;

    // ---- Wave 1: node + edge potentials for the block's 8 elems ----
    if (w == 1) {
        float v = 0.f;
        if (c < 8) {
            const int eglob = blockIdx.x * 8 + c;
            float nd2 = 0.f, edn = 0.f;
            int y[6];
            #pragma unroll
            for (int t = 0; t < 5; ++t) y[t] = Y[eglob * 20 + 5 * g + t];
            y[5] = (g < 3) ? Y[eglob * 20 + 5 * g + 5] : 0;
            #pragma unroll
            for (int t = 0; t < 5; ++t) {
                const int m = 5 * g + t;
                const unsigned wv = e_lds[(c * 20 + m) * 20 + (y[t] & 15)];
                nd2 += (y[t] < 16) ? lo16f(wv) : hi16f(wv);
                if (m < 19) edn += T[y[t] * 26 + y[t + 1]];
            }
            v = -LN2 * nd2 - edn;
        }
        #pragma unroll
        for (int d = 1; d <= 32; d <<= 1) v += __shfl_xor(v, d, 64);
        if (l == 0) part[blockIdx.x * 2 + 1] = v;
        return;
    }
    if (w != 0) return;

    // ---- Wave 0: MFMA-matvec recursion (verified), cols 0-7 real ----
    const int ce = c & 7;

    ABu A0, A1;
    #pragma unroll
    for (int jj = 0; jj < 8; ++jj) {
        const int kp = 4 * g + (jj & 3) + ((jj >> 2) << 4);
        float v0 = 0.f, v1 = 0.f;
        if (kp < 26) {
            v0 = __builtin_amdgcn_exp2f(T[kp * 26 + c] * C_SCALE);
            if (16 + c < 26) v1 = __builtin_amdgcn_exp2f(T[kp * 26 + 16 + c] * C_SCALE);
        }
        A0.u[jj] = f2bf(v0);
        A1.u[jj] = f2bf(v1);
    }

    u32x4 ev[20];
    #pragma unroll
    for (int m = 0; m < 20; ++m)
        ev[m] = *(const u32x4*)&e_lds[(ce * 20 + m) * 20 + 4 * g];

    f32x4 s0, s1;
    #pragma unroll
    for (int i = 0; i < 4; ++i) { s0[i] = lo16f(ev[0][i]); s1[i] = hi16f(ev[0][i]); }
    if (16 + 4 * g + 0 >= 26) s1[0] = NEGF;
    if (16 + 4 * g + 1 >= 26) s1[1] = NEGF;
    if (16 + 4 * g + 2 >= 26) s1[2] = NEGF;
    if (16 + 4 * g + 3 >= 26) s1[3] = NEGF;

    const f32x4 z = {0.f, 0.f, 0.f, 0.f};
    #pragma unroll
    for (int m = 0; m < 19; ++m) {
        const float mx8 = fmaxf(fmaxf(fmaxf(s0[0], s0[1]), fmaxf(s0[2], s0[3])),
                                fmaxf(fmaxf(s1[0], s1[1]), fmaxf(s1[2], s1[3])));
        const float mx = qmax(mx8);
        ABu B;
        B.u[0] = f2bf(__builtin_amdgcn_exp2f(s0[0] - mx));
        B.u[1] = f2bf(__builtin_amdgcn_exp2f(s0[1] - mx));
        B.u[2] = f2bf(__builtin_amdgcn_exp2f(s0[2] - mx));
        B.u[3] = f2bf(__builtin_amdgcn_exp2f(s0[3] - mx));
        B.u[4] = f2bf(__builtin_amdgcn_exp2f(s1[0] - mx));
        B.u[5] = f2bf(__builtin_amdgcn_exp2f(s1[1] - mx));
        B.u[6] = f2bf(__builtin_amdgcn_exp2f(s1[2] - mx));
        B.u[7] = f2bf(__builtin_amdgcn_exp2f(s1[3] - mx));
        f32x4 D0 = __builtin_amdgcn_mfma_f32_16x16x32_bf16(A0.b, B.b, z, 0, 0, 0);
        f32x4 D1 = __builtin_amdgcn_mfma_f32_16x16x32_bf16(A1.b, B.b, z, 0, 0, 0);
        #pragma unroll
        for (int i = 0; i < 4; ++i) {
            s0[i] = mx + __builtin_amdgcn_logf(D0[i]) + lo16f(ev[m + 1][i]);
            s1[i] = mx + __builtin_amdgcn_logf(D1[i]) + hi16f(ev[m + 1][i]);
        }
    }

    const float mxl = fmaxf(fmaxf(fmaxf(s0[0], s0[1]), fmaxf(s0[2], s0[3])),
                            fmaxf(fmaxf(s1[0], s1[1]), fmaxf(s1[2], s1[3])));
    const float mx2 = qmax(mxl);
    float sm = __builtin_amdgcn_exp2f(s0[0] - mx2) + __builtin_amdgcn_exp2f(s0[1] - mx2)
             + __builtin_amdgcn_exp2f(s0[2] - mx2) + __builtin_amdgcn_exp2f(s0[3] - mx2)
             + __builtin_amdgcn_exp2f(s1[0] - mx2) + __builtin_amdgcn_exp2f(s1[1] - mx2)
             + __builtin_amdgcn_exp2f(s1[2] - mx2) + __builtin_amdgcn_exp2f(s1[3] - mx2);
    sm = qsum(sm);
    const float logZ2 = mx2 + __builtin_amdgcn_logf(sm);

    // one logZ per real elem: lanes with g==0 and c<8
    float v = (g == 0 && c < 8) ? LN2 * logZ2 : 0.f;
    #pragma unroll
    for (int d = 1; d <= 32; d <<= 1) v += __shfl_xor(v, d, 64);
    if (l == 0) part[blockIdx.x * 2] = v;
}

__global__ __launch_bounds__(256) void reduce_kernel(
    const float* __restrict__ part, float* __restrict__ out, int n)
{
    __shared__ float s[4];
    const int tid = threadIdx.x;
    float v = 0.f;
    for (int i = tid; i < n; i += 256) v += part[i];
    #pragma unroll
    for (int d = 1; d <= 32; d <<= 1) v += __shfl_xor(v, d, 64);
    if ((tid & 63) == 0) s[tid >> 6] = v;
    __syncthreads();
    if (tid == 0) out[0] = s[0] + s[1] + s[2] + s[3];
}

extern "C" void kernel_launch(void* const* d_in, const int* in_sizes, int n_in,
                              void* d_out, int out_size, void* d_ws, size_t ws_size,
                              hipStream_t stream) {
    const float* X = (const float*)d_in[0];
    const int*   Y = (const int*)d_in[1];
    const float* W = (const float*)d_in[2];
    const float* T = (const float*)d_in[3];
    float* out = (float*)d_out;
    float* part = (float*)d_ws;            // 2048 floats

    const int B = in_sizes[1] / 20;        // 8192
    const int nblocks = B / 8;             // 1024 (8 elems per block)

    crf_kernel<<<nblocks, 256, 0, stream>>>(X, Y, W, T, part);
    reduce_kernel<<<1, 256, 0, stream>>>(part, out, nblocks * 2);
}